// Round 6
// baseline (721.879 us; speedup 1.0000x reference)
//
#include <hip/hip_runtime.h>

#define C_DIM 256
#define STEPS 20
#define ROWS_PER_WG 32
#define DRV_BASE 65536
#define SMEM_BYTES (65536 + 512 * 80)

typedef _Float16 f16;
typedef f16 f16x4 __attribute__((ext_vector_type(4)));
typedef f16 f16x8 __attribute__((ext_vector_type(8)));
typedef float f32x4 __attribute__((ext_vector_type(4)));

// ---------------------------------------------------------------------------
// prep: W'[k][n] = 0.5*W[k][n] + 0.5*K[(k-n+2) mod 256 if <5]
// stored as A-fragments of the TRANSPOSED gemm (A = W'^T):
//   frag f = mt*8+kb : lane l holds A[n = mt*16+(l&15)][k = kb*32+(l>>4)*8+j]
//   hi = f16(v) ; lo = f16((v-hi)*4096)
// ---------------------------------------------------------------------------
__global__ __launch_bounds__(256) void prep_w(const float* __restrict__ W,
                                              const float* __restrict__ Kl,
                                              f16* __restrict__ whi,
                                              f16* __restrict__ wlo)
{
    const int f = (int)(blockIdx.x * blockDim.x + threadIdx.x) >> 6;  // 0..127
    const int l = (int)threadIdx.x & 63;
    if (f >= 128) return;
    const int mt = f >> 3, kb = f & 7;
    const int n = mt * 16 + (l & 15);
    const int kbase = kb * 32 + (l >> 4) * 8;
    f16 h[8], lo[8];
    #pragma unroll
    for (int j = 0; j < 8; ++j) {
        const int k = kbase + j;
        float v = 0.5f * W[k * C_DIM + n];
        const int d = (k - n + 2) & (C_DIM - 1);
        if (d < 5) v += 0.5f * Kl[d];
        const f16 hh = (f16)v;
        h[j] = hh;
        lo[j] = (f16)((v - (float)hh) * 4096.0f);
    }
    const size_t off = (size_t)f * 512 + (size_t)l * 8;
    *(f16x8*)(whi + off) = *(f16x8*)h;
    *(f16x8*)(wlo + off) = *(f16x8*)lo;
}

// ---------------------------------------------------------------------------
// main: 512 thr = 8 waves. Transposed GEMM D[n][m] = W'^T x mapped^T.
// Wave w owns channel tiles mt = {2w, 2w+1}; W' hi/lo fragments reg-resident.
// Batch halves processed per-wave in slot order; waves 4..7 (ntSwap=1) have
// the slot->batch-half mapping SWAPPED so the two waves sharing a SIMD
// (w, w+4) anti-align their MFMA vs VALU phases (T5 setprio then pays).
// kb+1 operands are prefetched before kb's MFMA cluster; slot0's kb=7
// prefetches slot1's kb=0 (latency hides under slot0's physics tail).
//
// LDS: [0,64K) mapped planes as R5 (p = c ^ (m&7) swizzle, conflict-free at
// the wave64-b128 floor); [64K, 64K+40960) beta*drive spill, stride 80 B
// (16B-aligned, banks 4*(5l%8) -> conflict-free). Dynamic LDS 104 KiB.
// ---------------------------------------------------------------------------
__global__ __launch_bounds__(512, 2) void cml_main(
    const float* __restrict__ drive,
    const float* __restrict__ r_,
    const float* __restrict__ eps_,
    const float* __restrict__ beta_,
    const f16* __restrict__ whi,
    const f16* __restrict__ wlo,
    float* __restrict__ out)
{
    extern __shared__ char smem[];

    const int tid = (int)threadIdx.x;
    const int w   = tid >> 6;            // wave 0..7
    const int l   = tid & 63;
    const int kg  = l >> 4;              // 0..3
    const int cl  = l & 15;
    const int ntSwap = (w >> 2) & 1;     // waves 4-7: swapped slot mapping
    const size_t rowBase = (size_t)blockIdx.x * ROWS_PER_WG;
    const int drvBase = DRV_BASE + tid * 80;

    // slot u (compile-time) -> batch-half ntm[u] (runtime, wave-uniform)
    const int ntm0 = ntSwap;
    const int ntm1 = ntSwap ^ 1;

    // ---- one-time: W' A-fragments into registers (32 frags = 128 regs) ----
    f16x8 Wh[2][8], Wl[2][8];
    #pragma unroll
    for (int mti = 0; mti < 2; ++mti) {
        #pragma unroll
        for (int kb = 0; kb < 8; ++kb) {
            const size_t off = (size_t)((w * 2 + mti) * 8 + kb) * 512 + (size_t)l * 8;
            Wh[mti][kb] = *(const f16x8*)(whi + off);
            Wl[mti][kb] = *(const f16x8*)(wlo + off);
        }
    }

    // ---- one-time: per-channel params (ch = (2w+mti)*16 + kg*4 + r) ----
    float rr[2][4], P1[2][4], P2[2][4];
    #pragma unroll
    for (int mti = 0; mti < 2; ++mti) {
        const int ch0 = (w * 2 + mti) * 16 + kg * 4;
        #pragma unroll
        for (int r = 0; r < 4; ++r) {
            const int ch = ch0 + r;
            const float rv = r_[ch], ev = eps_[ch], bv = beta_[ch];
            rr[mti][r] = rv;
            P1[mti][r] = (1.0f - bv) * (1.0f - ev);
            P2[mti][r] = (1.0f - bv) * ev;
        }
    }

    // ---- one-time: drive -> g ; beta*drive -> LDS ----
    float g[2][2][4], m_[2][2][4];
    {
        const int mrow[2] = { ntm0 * 16 + cl, ntm1 * 16 + cl };
        #pragma unroll
        for (int mti = 0; mti < 2; ++mti) {
            const int ch0 = (w * 2 + mti) * 16 + kg * 4;
            #pragma unroll
            for (int u = 0; u < 2; ++u) {
                const size_t row = rowBase + (size_t)mrow[u];
                const f32x4 d4 = *(const f32x4*)(drive + row * C_DIM + ch0);
                f32x4 dv;
                #pragma unroll
                for (int r = 0; r < 4; ++r) {
                    g[mti][u][r] = d4[r];
                    dv[r] = beta_[ch0 + r] * d4[r];
                }
                *(f32x4*)(smem + drvBase + ((mti * 2 + u) << 4)) = dv;
            }
        }
    }

    // ---- precompute LDS addresses (swizzle p = c ^ (m&7)) ----
    int rbase[2], woff[2][2];
    #pragma unroll
    for (int u = 0; u < 2; ++u) {
        const int m = (u ? ntm1 : ntm0) * 16 + cl;
        rbase[u] = (m << 9) + ((kg ^ (m & 7)) << 4);
        #pragma unroll
        for (int mti = 0; mti < 2; ++mti) {
            const int c = (w * 2 + mti) * 2 + (kg >> 1);
            const int p = c ^ (m & 7);
            woff[mti][u] = (m << 9) + (p << 4) + ((kg & 1) << 3);
        }
    }

    // ---- prologue: E for step 0 into buf0 ----
    #pragma unroll
    for (int mti = 0; mti < 2; ++mti) {
        #pragma unroll
        for (int u = 0; u < 2; ++u) {
            f16x4 hv, lv;
            #pragma unroll
            for (int r = 0; r < 4; ++r) {
                const float gv = g[mti][u][r];
                const float mv = rr[mti][r] * gv * (1.0f - gv);
                m_[mti][u][r] = mv;
                const f16 hh = (f16)mv;
                hv[r] = hh;
                lv[r] = (f16)((mv - (float)hh) * 4096.0f);
            }
            *(f16x4*)(smem + woff[mti][u]) = hv;
            *(f16x4*)(smem + woff[mti][u] + 16384) = lv;
        }
    }

    #pragma unroll 1
    for (int s = 0; s < STEPS; ++s) {
        __syncthreads();                       // planes for step s complete
        const int rb = (s & 1) << 15;          // current buffer
        const int wb = rb ^ 32768;             // next buffer
        const int lastStep = (s == STEPS - 1);

        const int Ab0 = rbase[0] | rb;
        const int Ab1 = rbase[1] | rb;

        f16x8 bh = *(const f16x8*)(smem + Ab0);
        f16x8 bl = *(const f16x8*)(smem + Ab0 + 16384);

        #pragma unroll
        for (int u = 0; u < 2; ++u) {
            const int Ab = u ? Ab1 : Ab0;
            f32x4 acch[2], accl[2];
            acch[0] = (f32x4)0.0f; acch[1] = (f32x4)0.0f;
            accl[0] = (f32x4)0.0f; accl[1] = (f32x4)0.0f;

            #pragma unroll
            for (int kb = 0; kb < 8; ++kb) {
                f16x8 nbh, nbl;
                const bool hasNext = (kb < 7) || (u == 0);
                const int na = (kb < 7) ? (Ab ^ ((kb + 1) << 6)) : Ab1;
                if (hasNext) {
                    nbh = *(const f16x8*)(smem + na);
                    nbl = *(const f16x8*)(smem + na + 16384);
                }
                __builtin_amdgcn_s_setprio(1);
                acch[0] = __builtin_amdgcn_mfma_f32_16x16x32_f16(Wh[0][kb], bh, acch[0], 0, 0, 0);
                acch[1] = __builtin_amdgcn_mfma_f32_16x16x32_f16(Wh[1][kb], bh, acch[1], 0, 0, 0);
                accl[0] = __builtin_amdgcn_mfma_f32_16x16x32_f16(Wl[0][kb], bh, accl[0], 0, 0, 0);
                accl[1] = __builtin_amdgcn_mfma_f32_16x16x32_f16(Wl[1][kb], bh, accl[1], 0, 0, 0);
                accl[0] = __builtin_amdgcn_mfma_f32_16x16x32_f16(Wh[0][kb], bl, accl[0], 0, 0, 0);
                accl[1] = __builtin_amdgcn_mfma_f32_16x16x32_f16(Wh[1][kb], bl, accl[1], 0, 0, 0);
                __builtin_amdgcn_s_setprio(0);
                if (hasNext) { bh = nbh; bl = nbl; }
            }

            // ---- tail: physics (+ next-step map/split/write unless last) ----
            #pragma unroll
            for (int mti = 0; mti < 2; ++mti) {
                const f32x4 dv = *(const f32x4*)(smem + drvBase + ((mti * 2 + u) << 4));
                f16x4 hv, lv;
                #pragma unroll
                for (int r = 0; r < 4; ++r) {
                    const float coupled = fmaf(accl[mti][r], 1.0f / 4096.0f, acch[mti][r]);
                    const float gn = fmaf(P1[mti][r], m_[mti][u][r],
                                     fmaf(P2[mti][r], coupled, dv[r]));
                    g[mti][u][r] = gn;
                    const float mv = rr[mti][r] * gn * (1.0f - gn);
                    m_[mti][u][r] = mv;
                    const f16 hh = (f16)mv;
                    hv[r] = hh;
                    lv[r] = (f16)((mv - (float)hh) * 4096.0f);
                }
                if (!lastStep) {
                    *(f16x4*)(smem + (woff[mti][u] | wb)) = hv;
                    *(f16x4*)(smem + (woff[mti][u] | wb) + 16384) = lv;
                }
            }
        }
    }

    // ---- epilogue: clip + store ----
    {
        const int mrow[2] = { ntm0 * 16 + cl, ntm1 * 16 + cl };
        #pragma unroll
        for (int mti = 0; mti < 2; ++mti) {
            const int ch0 = (w * 2 + mti) * 16 + kg * 4;
            #pragma unroll
            for (int u = 0; u < 2; ++u) {
                const size_t row = rowBase + (size_t)mrow[u];
                f32x4 o;
                #pragma unroll
                for (int r = 0; r < 4; ++r) {
                    o[r] = fminf(fmaxf(g[mti][u][r], 1e-4f), 1.0f - 1e-4f);
                }
                *(f32x4*)(out + row * C_DIM + ch0) = o;
            }
        }
    }
}

extern "C" void kernel_launch(void* const* d_in, const int* in_sizes, int n_in,
                              void* d_out, int out_size, void* d_ws, size_t ws_size,
                              hipStream_t stream) {
    (void)n_in; (void)ws_size; (void)out_size;
    const float* drive = (const float*)d_in[0];
    const float* r     = (const float*)d_in[1];
    const float* eps   = (const float*)d_in[2];
    const float* beta  = (const float*)d_in[3];
    const float* Kl    = (const float*)d_in[4];
    const float* W     = (const float*)d_in[5];
    float* out = (float*)d_out;

    f16* whi = (f16*)d_ws;            // 128 KiB
    f16* wlo = whi + 65536;           // 128 KiB

    prep_w<<<dim3(32), dim3(256), 0, stream>>>(W, Kl, whi, wlo);

    hipFuncSetAttribute((const void*)cml_main,
                        hipFuncAttributeMaxDynamicSharedMemorySize, SMEM_BYTES);

    const int nrows = in_sizes[0] / C_DIM;        // 131072
    cml_main<<<dim3((unsigned)(nrows / ROWS_PER_WG)), dim3(512), SMEM_BYTES, stream>>>(
        drive, r, eps, beta, whi, wlo, out);
}